// Round 1
// baseline (266.531 us; speedup 1.0000x reference)
//
#include <hip/hip_runtime.h>
#include <cstdint>
#include <cstddef>

#define D_DIM   256
#define B_ROWS  1024
#define C_CLS   200000
#define S_SC    64.0f
#define COS_M_F 0.87758256189037271612f
#define SIN_M_F 0.47942553860420300027f
#define EPS_F   1e-8f

#define BM 128
#define BN 128
#define BK 64
#define MT (B_ROWS / BM)            /* 8    */
#define NT ((C_CLS + BN - 1) / BN)  /* 1563 */
#define NBLK (MT * NT)              /* 12504 = 8*1563 exactly */

typedef short bf16x8 __attribute__((ext_vector_type(8)));
typedef float f32x4  __attribute__((ext_vector_type(4)));

__device__ __forceinline__ unsigned short f2bf(float x) {
  unsigned int u = __builtin_bit_cast(unsigned int, x);
  return (unsigned short)((u + 0x8000u) >> 16);   // round-to-nearest (biased ties)
}
__device__ __forceinline__ float bf2f(unsigned short u) {
  return __builtin_bit_cast(float, ((unsigned int)u) << 16);
}

// ---------------- kernel 1: normalize embeddings -> bf16 in ws ----------------
__global__ void k_norm_embed(const float* __restrict__ emb,
                             unsigned short* __restrict__ ebf) {
  int wid = threadIdx.x >> 6, lane = threadIdx.x & 63;
  int row = (blockIdx.x << 2) + wid;                // 4 rows / block
  const float4 v = *reinterpret_cast<const float4*>(emb + (size_t)row * D_DIM + lane * 4);
  float ss = v.x * v.x + v.y * v.y + v.z * v.z + v.w * v.w;
#pragma unroll
  for (int m = 32; m >= 1; m >>= 1) ss += __shfl_xor(ss, m, 64);
  float inv = 1.0f / fmaxf(sqrtf(ss), 1e-12f);
  ushort4 o;
  o.x = f2bf(v.x * inv); o.y = f2bf(v.y * inv);
  o.z = f2bf(v.z * inv); o.w = f2bf(v.w * inv);
  *reinterpret_cast<ushort4*>(ebf + (size_t)row * D_DIM + lane * 4) = o;
}

// ---------------- kernel 2: prototype inverse norms ---------------------------
__global__ void k_proto_norm(const float* __restrict__ proto,
                             float* __restrict__ invn) {
  int wid = threadIdx.x >> 6, lane = threadIdx.x & 63;
  int row = (blockIdx.x << 2) + wid;                // 4 rows / block, 50000 blocks
  const float4 v = *reinterpret_cast<const float4*>(proto + (size_t)row * D_DIM + lane * 4);
  float ss = v.x * v.x + v.y * v.y + v.z * v.z + v.w * v.w;
#pragma unroll
  for (int m = 32; m >= 1; m >>= 1) ss += __shfl_xor(ss, m, 64);
  if (lane == 0) invn[row] = 1.0f / fmaxf(sqrtf(ss), 1e-12f);
}

// ---------------- kernel 3: fused GEMM + exp + row-sum ------------------------
// C[b,c] = sum_d ebf[b,d]*bf16(proto[c,d]) ; cos = C*invn[c] ; sums[b] += exp(S*cos)
__global__ __launch_bounds__(256, 3) void k_gemm_exp(
    const unsigned short* __restrict__ ebf, const float* __restrict__ proto,
    const float* __restrict__ invn, float* __restrict__ sums) {
  __shared__ short As[BM * BK];     // 16 KiB, row = 128 B, XOR-swizzled 16B slots
  __shared__ short Bs[BN * BK];     // 16 KiB
  __shared__ float rowsum[BM];

  const int t = threadIdx.x;
  // XCD-contiguous swizzle: per-XCD contiguous w-range, m fastest within it.
  int bid = (int)blockIdx.x;
  int w = (bid & 7) * NT + (bid >> 3);   // bijective since NBLK = 8*NT
  const int ntile = w >> 3;
  const int mtile = w & 7;
  const int m0 = mtile * BM;
  const int n0 = ntile * BN;
  const int lane = t & 63, wid = t >> 6;
  const int wm = wid >> 1, wn = wid & 1;    // 2x2 wave grid, 64x64 per wave

  if (t < BM) rowsum[t] = 0.0f;

  f32x4 acc[4][4];
  const f32x4 fz = {0.0f, 0.0f, 0.0f, 0.0f};
#pragma unroll
  for (int i = 0; i < 4; ++i)
#pragma unroll
    for (int j = 0; j < 4; ++j) acc[i][j] = fz;

  const int srow = t >> 3;       // 0..31  (+ j*32)
  const int sphys = t & 7;       // physical 16B slot

  for (int k0 = 0; k0 < D_DIM; k0 += BK) {
    // ---- stage A (bf16 e) via global_load_lds, source pre-swizzled ----
#pragma unroll
    for (int j = 0; j < 4; ++j) {
      int r = j * 32 + srow;
      int sl = sphys ^ (r & 7);
      const unsigned short* g = ebf + (size_t)(m0 + r) * D_DIM + k0 + sl * 8;
      __builtin_amdgcn_global_load_lds(
          (const __attribute__((address_space(1))) unsigned int*)(const void*)g,
          (__attribute__((address_space(3))) unsigned int*)(void*)(As + j * 2048 + wid * 512),
          16, 0, 0);
    }
    // ---- stage B (fp32 proto -> bf16), swizzled ds_write ----
#pragma unroll
    for (int j = 0; j < 4; ++j) {
      int r = j * 32 + srow;
      int sl = sphys ^ (r & 7);
      int c = n0 + r;
      bf16x8 wv;
      if (c < C_CLS) {
        const float* g = proto + (size_t)c * D_DIM + k0 + sl * 8;
        float4 u0 = *reinterpret_cast<const float4*>(g);
        float4 u1 = *reinterpret_cast<const float4*>(g + 4);
        wv[0] = (short)f2bf(u0.x); wv[1] = (short)f2bf(u0.y);
        wv[2] = (short)f2bf(u0.z); wv[3] = (short)f2bf(u0.w);
        wv[4] = (short)f2bf(u1.x); wv[5] = (short)f2bf(u1.y);
        wv[6] = (short)f2bf(u1.z); wv[7] = (short)f2bf(u1.w);
      } else {
        wv = (bf16x8){0, 0, 0, 0, 0, 0, 0, 0};
      }
      *reinterpret_cast<bf16x8*>(Bs + j * 2048 + t * 8) = wv;  // linear 16B/thread
    }
    __syncthreads();

    // ---- compute: 2 k-substeps of 32, 16 MFMA each ----
#pragma unroll
    for (int ks = 0; ks < 2; ++ks) {
      bf16x8 af[4], bfr[4];
#pragma unroll
      for (int mi = 0; mi < 4; ++mi) {
        int r = wm * 64 + mi * 16 + (lane & 15);
        int sl = (ks * 4 + (lane >> 4)) ^ (r & 7);
        af[mi] = *reinterpret_cast<const bf16x8*>(As + r * 64 + sl * 8);
      }
#pragma unroll
      for (int ni = 0; ni < 4; ++ni) {
        int r = wn * 64 + ni * 16 + (lane & 15);
        int sl = (ks * 4 + (lane >> 4)) ^ (r & 7);
        bfr[ni] = *reinterpret_cast<const bf16x8*>(Bs + r * 64 + sl * 8);
      }
#pragma unroll
      for (int mi = 0; mi < 4; ++mi)
#pragma unroll
        for (int ni = 0; ni < 4; ++ni)
          acc[mi][ni] = __builtin_amdgcn_mfma_f32_16x16x32_bf16(
              af[mi], bfr[ni], acc[mi][ni], 0, 0, 0);
    }
    __syncthreads();
  }

  // ---- epilogue: cos -> exp -> per-row sums ----
  // elem (mi,ni,j): row = wm*64+mi*16+(lane>>4)*4+j ; col = n0+wn*64+ni*16+(lane&15)
  float invv[4], vmask[4];
  const int ccol = n0 + wn * 64 + (lane & 15);
#pragma unroll
  for (int ni = 0; ni < 4; ++ni) {
    int c = ccol + ni * 16;
    bool v = (c < C_CLS);
    invv[ni] = v ? invn[c] : 0.0f;
    vmask[ni] = v ? 1.0f : 0.0f;
  }
#pragma unroll
  for (int mi = 0; mi < 4; ++mi) {
#pragma unroll
    for (int j = 0; j < 4; ++j) {
      float rs = 0.0f;
#pragma unroll
      for (int ni = 0; ni < 4; ++ni)
        rs += vmask[ni] * __expf(S_SC * invv[ni] * acc[mi][ni][j]);
      rs += __shfl_xor(rs, 1, 64);
      rs += __shfl_xor(rs, 2, 64);
      rs += __shfl_xor(rs, 4, 64);
      rs += __shfl_xor(rs, 8, 64);
      if ((lane & 15) == 0)
        atomicAdd(&rowsum[wm * 64 + mi * 16 + ((lane >> 4) << 2) + j], rs);
    }
  }
  __syncthreads();
  if (t < BM) atomicAdd(&sums[m0 + t], rowsum[t]);
}

// ---------------- kernel 4: label column + final loss -------------------------
__global__ void k_finalize(const unsigned short* __restrict__ ebf,
                           const float* __restrict__ proto,
                           const float* __restrict__ invn,
                           const int* __restrict__ labels,
                           const float* __restrict__ sums,
                           float* __restrict__ out) {
  __shared__ float part[4];
  int wid = threadIdx.x >> 6, lane = threadIdx.x & 63;
  int b = (blockIdx.x << 2) + wid;
  int lab = labels[b];
  const unsigned short* e = ebf + (size_t)b * D_DIM;
  const float* p = proto + (size_t)lab * D_DIM;
  float dot = 0.0f;
#pragma unroll
  for (int i = 0; i < 4; ++i) {
    int d = lane * 4 + i;
    dot += bf2f(e[d]) * bf2f(f2bf(p[d]));   // match GEMM's bf16 rounding
  }
#pragma unroll
  for (int m = 32; m >= 1; m >>= 1) dot += __shfl_xor(dot, m, 64);
  if (lane == 0) {
    float cs = dot * invn[lab];
    float sn = sqrtf(fmaxf(1.0f - cs * cs, EPS_F));
    sn = fminf(fmaxf(sn, EPS_F), 1.0f - EPS_F);
    float phi = cs * COS_M_F - sn * SIN_M_F;
    float sp = S_SC * phi;
    float total = sums[b] - __expf(S_SC * cs) + __expf(sp);
    part[wid] = logf(total) - sp;
  }
  __syncthreads();
  if (threadIdx.x == 0) {
    float s = part[0] + part[1] + part[2] + part[3];
    atomicAdd(out, s * (1.0f / (float)B_ROWS));
  }
}

// ---------------- launcher ----------------------------------------------------
extern "C" void kernel_launch(void* const* d_in, const int* in_sizes, int n_in,
                              void* d_out, int out_size, void* d_ws, size_t ws_size,
                              hipStream_t stream) {
  const float* emb   = (const float*)d_in[0];
  const int*   labels = (const int*)d_in[1];
  const float* proto = (const float*)d_in[2];
  float* out = (float*)d_out;

  char* ws = (char*)d_ws;
  unsigned short* ebf = (unsigned short*)ws;                   // 1024*256*2 = 524288 B
  float* invn = (float*)(ws + 524288);                         // 200000*4  = 800000 B
  float* sums = (float*)(ws + 524288 + 800000);                // 1024*4    =   4096 B

  hipMemsetAsync(sums, 0, B_ROWS * sizeof(float), stream);
  hipMemsetAsync(out, 0, sizeof(float), stream);

  k_norm_embed<<<B_ROWS / 4, 256, 0, stream>>>(emb, ebf);
  k_proto_norm<<<C_CLS / 4, 256, 0, stream>>>(proto, invn);
  k_gemm_exp<<<NBLK, 256, 0, stream>>>(ebf, proto, invn, sums);
  k_finalize<<<B_ROWS / 4, 256, 0, stream>>>(ebf, proto, invn, labels, sums, out);
}

// Round 2
// 203.147 us; speedup vs baseline: 1.3120x; 1.3120x over previous
//
#include <hip/hip_runtime.h>
#include <cstdint>
#include <cstddef>

#define D_DIM   256
#define B_ROWS  1024
#define C_CLS   200000
#define S_SC    64.0f
#define COS_M_F 0.87758256189037271612f
#define SIN_M_F 0.47942553860420300027f
#define EPS_F   1e-8f

typedef short bf16x8 __attribute__((ext_vector_type(8)));
typedef float f32x4  __attribute__((ext_vector_type(4)));

__device__ __forceinline__ unsigned short f2bf(float x) {
  unsigned int u = __builtin_bit_cast(unsigned int, x);
  return (unsigned short)((u + 0x8000u) >> 16);
}
__device__ __forceinline__ float bf2f(unsigned short u) {
  return __builtin_bit_cast(float, ((unsigned int)u) << 16);
}

// ---------------- kernel 1: normalize embeddings -> bf16 in ws ----------------
__global__ void k_norm_embed(const float* __restrict__ emb,
                             unsigned short* __restrict__ ebf) {
  int wid = threadIdx.x >> 6, lane = threadIdx.x & 63;
  int row = (blockIdx.x << 2) + wid;
  const float4 v = *reinterpret_cast<const float4*>(emb + (size_t)row * D_DIM + lane * 4);
  float ss = v.x * v.x + v.y * v.y + v.z * v.z + v.w * v.w;
#pragma unroll
  for (int m = 32; m >= 1; m >>= 1) ss += __shfl_xor(ss, m, 64);
  float inv = 1.0f / fmaxf(sqrtf(ss), 1e-12f);
  ushort4 o;
  o.x = f2bf(v.x * inv); o.y = f2bf(v.y * inv);
  o.z = f2bf(v.z * inv); o.w = f2bf(v.w * inv);
  *reinterpret_cast<ushort4*>(ebf + (size_t)row * D_DIM + lane * 4) = o;
}

// ================================ PATH A =====================================
// pre-normalized bf16 prototypes in ws; GEMM stages both operands via
// global_load_lds; wave tile 64x128.

#define BM   128
#define BNA  256
#define BK   64
#define NTA  782                   /* ceil(200000/256) */
#define CPAD (NTA * BNA)           /* 200192 */
#define NBLKA (8 * NTA)            /* 6256 */

// normalize prototypes -> bf16(p/||p||), zero-fill pad rows [C_CLS, CPAD)
__global__ void k_proto_norm_cvt(const float* __restrict__ proto,
                                 unsigned short* __restrict__ pbf) {
  int wid = threadIdx.x >> 6, lane = threadIdx.x & 63;
  int row = (blockIdx.x << 2) + wid;               // grid = CPAD/4 blocks
  if (row >= C_CLS) {
    *reinterpret_cast<ushort4*>(pbf + (size_t)row * D_DIM + lane * 4) =
        (ushort4){0, 0, 0, 0};
    return;
  }
  const float4 v = *reinterpret_cast<const float4*>(proto + (size_t)row * D_DIM + lane * 4);
  float ss = v.x * v.x + v.y * v.y + v.z * v.z + v.w * v.w;
#pragma unroll
  for (int m = 32; m >= 1; m >>= 1) ss += __shfl_xor(ss, m, 64);
  float inv = 1.0f / fmaxf(sqrtf(ss), 1e-12f);
  ushort4 o;
  o.x = f2bf(v.x * inv); o.y = f2bf(v.y * inv);
  o.z = f2bf(v.z * inv); o.w = f2bf(v.w * inv);
  *reinterpret_cast<ushort4*>(pbf + (size_t)row * D_DIM + lane * 4) = o;
}

// fused GEMM + exp + row-sum, both operands bf16 via global_load_lds
__global__ __launch_bounds__(256, 2) void k_gemm_exp_a(
    const unsigned short* __restrict__ ebf, const unsigned short* __restrict__ pbf,
    float* __restrict__ sums) {
  __shared__ short As[BM * BK];      // 16 KiB, row = 128 B, XOR-swizzled 16B slots
  __shared__ short Bs[BNA * BK];     // 32 KiB
  __shared__ float rowsum[BM];

  const int t = threadIdx.x;
  int bid = (int)blockIdx.x;
  int w = (bid & 7) * NTA + (bid >> 3);   // bijective: NBLKA = 8*NTA
  const int ntile = w >> 3;
  const int mtile = w & 7;
  const int m0 = mtile * BM;
  const int n0 = ntile * BNA;
  const int lane = t & 63, wid = t >> 6;
  const int wm = wid >> 1, wn = wid & 1;    // 2x2 wave grid, wave tile 64x128

  if (t < BM) rowsum[t] = 0.0f;

  f32x4 acc[4][8];
  const f32x4 fz = {0.0f, 0.0f, 0.0f, 0.0f};
#pragma unroll
  for (int i = 0; i < 4; ++i)
#pragma unroll
    for (int j = 0; j < 8; ++j) acc[i][j] = fz;

  const int srow = t >> 3;       // 0..31
  const int sphys = t & 7;       // physical 16B slot

  for (int k0 = 0; k0 < D_DIM; k0 += BK) {
    // ---- stage A (128 rows) ----
#pragma unroll
    for (int j = 0; j < 4; ++j) {
      int r = j * 32 + srow;
      int sl = sphys ^ (r & 7);
      const unsigned short* g = ebf + (size_t)(m0 + r) * D_DIM + k0 + sl * 8;
      __builtin_amdgcn_global_load_lds(
          (const __attribute__((address_space(1))) unsigned int*)(const void*)g,
          (__attribute__((address_space(3))) unsigned int*)(void*)(As + j * 2048 + wid * 512),
          16, 0, 0);
    }
    // ---- stage B (256 rows) ----
#pragma unroll
    for (int j = 0; j < 8; ++j) {
      int r = j * 32 + srow;
      int sl = sphys ^ (r & 7);
      const unsigned short* g = pbf + (size_t)(n0 + r) * D_DIM + k0 + sl * 8;
      __builtin_amdgcn_global_load_lds(
          (const __attribute__((address_space(1))) unsigned int*)(const void*)g,
          (__attribute__((address_space(3))) unsigned int*)(void*)(Bs + j * 2048 + wid * 512),
          16, 0, 0);
    }
    __syncthreads();

#pragma unroll
    for (int ks = 0; ks < 2; ++ks) {
      bf16x8 af[4];
#pragma unroll
      for (int mi = 0; mi < 4; ++mi) {
        int r = wm * 64 + mi * 16 + (lane & 15);
        int sl = (ks * 4 + (lane >> 4)) ^ (r & 7);
        af[mi] = *reinterpret_cast<const bf16x8*>(As + r * 64 + sl * 8);
      }
#pragma unroll
      for (int ni = 0; ni < 8; ++ni) {
        int r = wn * 128 + ni * 16 + (lane & 15);
        int sl = (ks * 4 + (lane >> 4)) ^ (r & 7);
        bf16x8 bfr = *reinterpret_cast<const bf16x8*>(Bs + r * 64 + sl * 8);
#pragma unroll
        for (int mi = 0; mi < 4; ++mi)
          acc[mi][ni] = __builtin_amdgcn_mfma_f32_16x16x32_bf16(
              af[mi], bfr, acc[mi][ni], 0, 0, 0);
      }
    }
    __syncthreads();
  }

  // ---- epilogue: exp -> per-row sums (pbf pre-normalized: no invn needed) ----
  float vmask[8];
  const int ccol = n0 + wn * 128 + (lane & 15);
#pragma unroll
  for (int ni = 0; ni < 8; ++ni) vmask[ni] = (ccol + ni * 16 < C_CLS) ? 1.0f : 0.0f;
#pragma unroll
  for (int mi = 0; mi < 4; ++mi) {
#pragma unroll
    for (int j = 0; j < 4; ++j) {
      float rs = 0.0f;
#pragma unroll
      for (int ni = 0; ni < 8; ++ni)
        rs += vmask[ni] * __expf(S_SC * acc[mi][ni][j]);
      rs += __shfl_xor(rs, 1, 64);
      rs += __shfl_xor(rs, 2, 64);
      rs += __shfl_xor(rs, 4, 64);
      rs += __shfl_xor(rs, 8, 64);
      if ((lane & 15) == 0)
        atomicAdd(&rowsum[wm * 64 + mi * 16 + ((lane >> 4) << 2) + j], rs);
    }
  }
  __syncthreads();
  if (t < BM) atomicAdd(&sums[m0 + t], rowsum[t]);
}

__global__ void k_finalize_a(const unsigned short* __restrict__ ebf,
                             const unsigned short* __restrict__ pbf,
                             const int* __restrict__ labels,
                             const float* __restrict__ sums,
                             float* __restrict__ out) {
  __shared__ float part[4];
  int wid = threadIdx.x >> 6, lane = threadIdx.x & 63;
  int b = (blockIdx.x << 2) + wid;
  int lab = labels[b];
  const unsigned short* e = ebf + (size_t)b * D_DIM;
  const unsigned short* p = pbf + (size_t)lab * D_DIM;
  float dot = 0.0f;
#pragma unroll
  for (int i = 0; i < 4; ++i) {
    int d = lane * 4 + i;
    dot += bf2f(e[d]) * bf2f(p[d]);
  }
#pragma unroll
  for (int m = 32; m >= 1; m >>= 1) dot += __shfl_xor(dot, m, 64);
  if (lane == 0) {
    float cs = dot;
    float sn = sqrtf(fmaxf(1.0f - cs * cs, EPS_F));
    sn = fminf(fmaxf(sn, EPS_F), 1.0f - EPS_F);
    float phi = cs * COS_M_F - sn * SIN_M_F;
    float sp = S_SC * phi;
    float total = sums[b] - __expf(S_SC * cs) + __expf(sp);
    part[wid] = logf(total) - sp;
  }
  __syncthreads();
  if (threadIdx.x == 0) {
    float s = part[0] + part[1] + part[2] + part[3];
    atomicAdd(out, s * (1.0f / (float)B_ROWS));
  }
}

// ================================ PATH B (fallback, R0-proven) ===============
#define BNB 128
#define NTB 1563
#define NBLKB (8 * NTB)

__global__ void k_proto_norm(const float* __restrict__ proto,
                             float* __restrict__ invn) {
  int wid = threadIdx.x >> 6, lane = threadIdx.x & 63;
  int row = (blockIdx.x << 2) + wid;
  const float4 v = *reinterpret_cast<const float4*>(proto + (size_t)row * D_DIM + lane * 4);
  float ss = v.x * v.x + v.y * v.y + v.z * v.z + v.w * v.w;
#pragma unroll
  for (int m = 32; m >= 1; m >>= 1) ss += __shfl_xor(ss, m, 64);
  if (lane == 0) invn[row] = 1.0f / fmaxf(sqrtf(ss), 1e-12f);
}

__global__ __launch_bounds__(256, 3) void k_gemm_exp_b(
    const unsigned short* __restrict__ ebf, const float* __restrict__ proto,
    const float* __restrict__ invn, float* __restrict__ sums) {
  __shared__ short As[BM * BK];
  __shared__ short Bs[BNB * BK];
  __shared__ float rowsum[BM];

  const int t = threadIdx.x;
  int bid = (int)blockIdx.x;
  int w = (bid & 7) * NTB + (bid >> 3);
  const int ntile = w >> 3;
  const int mtile = w & 7;
  const int m0 = mtile * BM;
  const int n0 = ntile * BNB;
  const int lane = t & 63, wid = t >> 6;
  const int wm = wid >> 1, wn = wid & 1;

  if (t < BM) rowsum[t] = 0.0f;

  f32x4 acc[4][4];
  const f32x4 fz = {0.0f, 0.0f, 0.0f, 0.0f};
#pragma unroll
  for (int i = 0; i < 4; ++i)
#pragma unroll
    for (int j = 0; j < 4; ++j) acc[i][j] = fz;

  const int srow = t >> 3;
  const int sphys = t & 7;

  for (int k0 = 0; k0 < D_DIM; k0 += BK) {
#pragma unroll
    for (int j = 0; j < 4; ++j) {
      int r = j * 32 + srow;
      int sl = sphys ^ (r & 7);
      const unsigned short* g = ebf + (size_t)(m0 + r) * D_DIM + k0 + sl * 8;
      __builtin_amdgcn_global_load_lds(
          (const __attribute__((address_space(1))) unsigned int*)(const void*)g,
          (__attribute__((address_space(3))) unsigned int*)(void*)(As + j * 2048 + wid * 512),
          16, 0, 0);
    }
#pragma unroll
    for (int j = 0; j < 4; ++j) {
      int r = j * 32 + srow;
      int sl = sphys ^ (r & 7);
      int c = n0 + r;
      bf16x8 wv;
      if (c < C_CLS) {
        const float* g = proto + (size_t)c * D_DIM + k0 + sl * 8;
        float4 u0 = *reinterpret_cast<const float4*>(g);
        float4 u1 = *reinterpret_cast<const float4*>(g + 4);
        wv[0] = (short)f2bf(u0.x); wv[1] = (short)f2bf(u0.y);
        wv[2] = (short)f2bf(u0.z); wv[3] = (short)f2bf(u0.w);
        wv[4] = (short)f2bf(u1.x); wv[5] = (short)f2bf(u1.y);
        wv[6] = (short)f2bf(u1.z); wv[7] = (short)f2bf(u1.w);
      } else {
        wv = (bf16x8){0, 0, 0, 0, 0, 0, 0, 0};
      }
      *reinterpret_cast<bf16x8*>(Bs + j * 2048 + t * 8) = wv;
    }
    __syncthreads();

#pragma unroll
    for (int ks = 0; ks < 2; ++ks) {
      bf16x8 af[4], bfr[4];
#pragma unroll
      for (int mi = 0; mi < 4; ++mi) {
        int r = wm * 64 + mi * 16 + (lane & 15);
        int sl = (ks * 4 + (lane >> 4)) ^ (r & 7);
        af[mi] = *reinterpret_cast<const bf16x8*>(As + r * 64 + sl * 8);
      }
#pragma unroll
      for (int ni = 0; ni < 4; ++ni) {
        int r = wn * 64 + ni * 16 + (lane & 15);
        int sl = (ks * 4 + (lane >> 4)) ^ (r & 7);
        bfr[ni] = *reinterpret_cast<const bf16x8*>(Bs + r * 64 + sl * 8);
      }
#pragma unroll
      for (int mi = 0; mi < 4; ++mi)
#pragma unroll
        for (int ni = 0; ni < 4; ++ni)
          acc[mi][ni] = __builtin_amdgcn_mfma_f32_16x16x32_bf16(
              af[mi], bfr[ni], acc[mi][ni], 0, 0, 0);
    }
    __syncthreads();
  }

  float invv[4], vmask[4];
  const int ccol = n0 + wn * 64 + (lane & 15);
#pragma unroll
  for (int ni = 0; ni < 4; ++ni) {
    int c = ccol + ni * 16;
    bool v = (c < C_CLS);
    invv[ni] = v ? invn[c] : 0.0f;
    vmask[ni] = v ? 1.0f : 0.0f;
  }
#pragma unroll
  for (int mi = 0; mi < 4; ++mi) {
#pragma unroll
    for (int j = 0; j < 4; ++j) {
      float rs = 0.0f;
#pragma unroll
      for (int ni = 0; ni < 4; ++ni)
        rs += vmask[ni] * __expf(S_SC * invv[ni] * acc[mi][ni][j]);
      rs += __shfl_xor(rs, 1, 64);
      rs += __shfl_xor(rs, 2, 64);
      rs += __shfl_xor(rs, 4, 64);
      rs += __shfl_xor(rs, 8, 64);
      if ((lane & 15) == 0)
        atomicAdd(&rowsum[wm * 64 + mi * 16 + ((lane >> 4) << 2) + j], rs);
    }
  }
  __syncthreads();
  if (t < BM) atomicAdd(&sums[m0 + t], rowsum[t]);
}

__global__ void k_finalize_b(const unsigned short* __restrict__ ebf,
                             const float* __restrict__ proto,
                             const float* __restrict__ invn,
                             const int* __restrict__ labels,
                             const float* __restrict__ sums,
                             float* __restrict__ out) {
  __shared__ float part[4];
  int wid = threadIdx.x >> 6, lane = threadIdx.x & 63;
  int b = (blockIdx.x << 2) + wid;
  int lab = labels[b];
  const unsigned short* e = ebf + (size_t)b * D_DIM;
  const float* p = proto + (size_t)lab * D_DIM;
  float dot = 0.0f;
#pragma unroll
  for (int i = 0; i < 4; ++i) {
    int d = lane * 4 + i;
    dot += bf2f(e[d]) * bf2f(f2bf(p[d]));
  }
#pragma unroll
  for (int m = 32; m >= 1; m >>= 1) dot += __shfl_xor(dot, m, 64);
  if (lane == 0) {
    float cs = dot * invn[lab];
    float sn = sqrtf(fmaxf(1.0f - cs * cs, EPS_F));
    sn = fminf(fmaxf(sn, EPS_F), 1.0f - EPS_F);
    float phi = cs * COS_M_F - sn * SIN_M_F;
    float sp = S_SC * phi;
    float total = sums[b] - __expf(S_SC * cs) + __expf(sp);
    part[wid] = logf(total) - sp;
  }
  __syncthreads();
  if (threadIdx.x == 0) {
    float s = part[0] + part[1] + part[2] + part[3];
    atomicAdd(out, s * (1.0f / (float)B_ROWS));
  }
}

// ---------------- launcher ----------------------------------------------------
extern "C" void kernel_launch(void* const* d_in, const int* in_sizes, int n_in,
                              void* d_out, int out_size, void* d_ws, size_t ws_size,
                              hipStream_t stream) {
  const float* emb    = (const float*)d_in[0];
  const int*   labels = (const int*)d_in[1];
  const float* proto  = (const float*)d_in[2];
  float* out = (float*)d_out;

  char* ws = (char*)d_ws;
  unsigned short* ebf = (unsigned short*)ws;                 // 524288 B
  float* sums = (float*)(ws + 524288);                       // 4096 B
  float* invn = (float*)(ws + 528384);                       // 800000 B (path B)
  const size_t pbf_off = 2097152;
  unsigned short* pbf = (unsigned short*)(ws + pbf_off);     // CPAD*256*2 B (path A)
  const size_t need_a = pbf_off + (size_t)CPAD * D_DIM * 2;  // ~104.6 MB

  hipMemsetAsync(sums, 0, B_ROWS * sizeof(float), stream);
  hipMemsetAsync(out, 0, sizeof(float), stream);

  k_norm_embed<<<B_ROWS / 4, 256, 0, stream>>>(emb, ebf);

  if (ws_size >= need_a) {
    k_proto_norm_cvt<<<CPAD / 4, 256, 0, stream>>>(proto, pbf);
    k_gemm_exp_a<<<NBLKA, 256, 0, stream>>>(ebf, pbf, sums);
    k_finalize_a<<<B_ROWS / 4, 256, 0, stream>>>(ebf, pbf, labels, sums, out);
  } else {
    k_proto_norm<<<C_CLS / 4, 256, 0, stream>>>(proto, invn);
    k_gemm_exp_b<<<NBLKB, 256, 0, stream>>>(ebf, proto, invn, sums);
    k_finalize_b<<<B_ROWS / 4, 256, 0, stream>>>(ebf, proto, invn, labels, sums, out);
  }
}